// Round 2
// baseline (79.503 us; speedup 1.0000x reference)
//
#include <hip/hip_runtime.h>
#include <math.h>

// S4D kernel generation: K[h,l] = 2*Re( sum_n Ck[h,n] * exp(dtA[h,n]*l) )
// H=1024, N2=32, L=4096. Output (H,L) fp32.
//
// One block per h, 256 threads; thread t owns l = t + 256*j, j=0..15.
// Per mode n we need s_j = Re(Ck * exp(dtA*(t+256j))) for j=0..15.
// With W = exp(dtA)^256, s_j = Re(u0 * W^j) obeys the stable real recurrence
//   s_j = p*s_{j-1} - q*s_{j-2},  p = 2*Re(W), q = |W|^2   (3 VALU ops/step).
// Anchors s_0, s_1 are computed from a fp64-reduced phase (HW v_sin/v_cos take
// revolutions, so fract of the fp64 revolution count feeds them directly).
// Per-(h,n) coefficients are prepped in fp64 by lanes 0..31 into LDS.

#define N2 32
#define L_LEN 4096
#define NTHREADS 256
#define JTILE (L_LEN / NTHREADS)  // 16

__global__ __launch_bounds__(NTHREADS) void s4d_gen_kernel(
    const float* __restrict__ log_dt,      // (H,)
    const float* __restrict__ Cri,         // (H, N2, 2)
    const float* __restrict__ log_A_real,  // (H, N2)
    const float* __restrict__ A_imag,      // (H, N2)
    float* __restrict__ out)               // (H, L)
{
  const int h = blockIdx.x;
  const int t = threadIdx.x;

  __shared__ double s_yrev[N2];  // phase revolutions per unit l
  __shared__ float s_x[N2], s_ckr[N2], s_cki[N2];
  __shared__ float s_Wr[N2], s_Wi[N2], s_p[N2], s_q[N2];

  if (t < N2) {
    const int n = t;
    const double dt = exp((double)log_dt[h]);
    const double Ar = -exp((double)log_A_real[h * N2 + n]);
    const double Ai = (double)A_imag[h * N2 + n];
    const double xr = dt * Ar;   // Re(dtA)  (negative)
    const double xi = dt * Ai;   // Im(dtA)
    const double ex = exp(xr);
    const double wr = ex * cos(xi);   // w = exp(dtA)
    const double wi = ex * sin(xi);
    // f = (w - 1) / A  via  (w-1)*conj(A)/|A|^2
    const double nr = wr - 1.0, ni = wi;
    const double inv = 1.0 / (Ar * Ar + Ai * Ai);
    const double fr = (nr * Ar + ni * Ai) * inv;
    const double fi = (ni * Ar - nr * Ai) * inv;
    // Ck = 2 * Cc * f   (fold the final factor of 2 here)
    const double c0 = (double)Cri[(h * N2 + n) * 2 + 0];
    const double c1 = (double)Cri[(h * N2 + n) * 2 + 1];
    s_ckr[n] = (float)(2.0 * (c0 * fr - c1 * fi));
    s_cki[n] = (float)(2.0 * (c0 * fi + c1 * fr));
    s_x[n]    = (float)xr;
    s_yrev[n] = xi * 0.15915494309189535;  // xi / (2*pi)
    // W = w^256 by 8 complex squarings in double
    double ar = wr, ai2 = wi;
#pragma unroll
    for (int k = 0; k < 8; ++k) {
      const double tr = ar * ar - ai2 * ai2;
      const double ti = 2.0 * ar * ai2;
      ar = tr; ai2 = ti;
    }
    s_Wr[n] = (float)ar;
    s_Wi[n] = (float)ai2;
    s_p[n]  = (float)(2.0 * ar);
    s_q[n]  = (float)(ar * ar + ai2 * ai2);
  }
  __syncthreads();

  float acc[JTILE];
#pragma unroll
  for (int j = 0; j < JTILE; ++j) acc[j] = 0.0f;

  const float  tf = (float)t;
  const double td = (double)t;

  for (int n = 0; n < N2; ++n) {
    // anchor u0 = Ck * exp(dtA * t); phase reduced in fp64 revolutions
    double ph = s_yrev[n] * td;
    ph -= floor(ph);                              // exact fract, in [0,1)
    const float frac = (float)ph;
    const float sn = __builtin_amdgcn_sinf(frac); // sin(2*pi*frac)
    const float cs = __builtin_amdgcn_cosf(frac);
    const float e  = __expf(s_x[n] * tf);
    const float vr = e * cs;
    const float vi = e * sn;
    const float ckr = s_ckr[n], cki = s_cki[n];
    const float ur = fmaf(ckr, vr, -(cki * vi));
    const float ui = fmaf(ckr, vi,  cki * vr);
    // s_0, s_1 then the real 2-term recurrence
    float s0 = ur;
    float s1 = fmaf(ur, s_Wr[n], -(ui * s_Wi[n]));
    acc[0] += s0;
    acc[1] += s1;
    const float p = s_p[n], q = s_q[n];
#pragma unroll
    for (int j = 2; j < JTILE; ++j) {
      const float s2 = fmaf(p, s1, -(q * s0));
      acc[j] += s2;
      s0 = s1; s1 = s2;
    }
  }

  float* o = out + (size_t)h * L_LEN + t;
#pragma unroll
  for (int j = 0; j < JTILE; ++j) o[j * NTHREADS] = acc[j];
}

extern "C" void kernel_launch(void* const* d_in, const int* in_sizes, int n_in,
                              void* d_out, int out_size, void* d_ws, size_t ws_size,
                              hipStream_t stream) {
  const float* log_dt     = (const float*)d_in[0];
  const float* Cri        = (const float*)d_in[1];
  const float* log_A_real = (const float*)d_in[2];
  const float* A_imag     = (const float*)d_in[3];
  // d_in[4] is L (scalar, device); problem size fixed at 4096.
  float* out = (float*)d_out;
  const int H = in_sizes[0];

  s4d_gen_kernel<<<dim3(H), dim3(NTHREADS), 0, stream>>>(
      log_dt, Cri, log_A_real, A_imag, out);
}